// Round 6
// baseline (320.135 us; speedup 1.0000x reference)
//
#include <hip/hip_runtime.h>
#include <math.h>

#define D_MODEL 512  // kernel assumes D=512 (64 lanes x 8 floats)

typedef float fx4 __attribute__((ext_vector_type(4)));

#define NTL(p) __builtin_nontemporal_load((const fx4*)(p))

__device__ __forceinline__ float dot8(const fx4& a0, const fx4& a1,
                                      const fx4& b0, const fx4& b1) {
    return a0.x * b0.x + a0.y * b0.y + a0.z * b0.z + a0.w * b0.w
         + a1.x * b1.x + a1.y * b1.y + a1.z * b1.z + a1.w * b1.w;
}

// Online-softmax update for a block of 4 rows held in registers.
__device__ __forceinline__ void process4(
    const fx4& r0a, const fx4& r0b, const fx4& r1a, const fx4& r1b,
    const fx4& r2a, const fx4& r2b, const fx4& r3a, const fx4& r3b,
    const fx4& wa, const fx4& wb,
    float& m, float& l, fx4& a0, fx4& a1)
{
    float d0 = dot8(r0a, r0b, wa, wb);
    float d1 = dot8(r1a, r1b, wa, wb);
    float d2 = dot8(r2a, r2b, wa, wb);
    float d3 = dot8(r3a, r3b, wa, wb);
    #pragma unroll
    for (int off = 32; off >= 1; off >>= 1) {   // 4 interleaved chains
        d0 += __shfl_xor(d0, off);
        d1 += __shfl_xor(d1, off);
        d2 += __shfl_xor(d2, off);
        d3 += __shfl_xor(d3, off);
    }
    const float mx = fmaxf(fmaxf(d0, d1), fmaxf(d2, d3));
    if (mx > m) {                        // wave-uniform, rare (~log RPW)
        const float sc = __expf(m - mx); // first hit: exp(-inf)=0, acc is 0
        l *= sc;
        a0 *= sc;
        a1 *= sc;
        m = mx;
    }
    const float p0 = __expf(d0 - m);
    const float p1 = __expf(d1 - m);
    const float p2 = __expf(d2 - m);
    const float p3 = __expf(d3 - m);
    l += (p0 + p1) + (p2 + p3);
    a0 += p0 * r0a; a1 += p0 * r0b;
    a0 += p1 * r1a; a1 += p1 * r1b;
    a0 += p2 * r2a; a1 += p2 * r2b;
    a0 += p3 * r3a; a1 += p3 * r3b;
}

// Fused: online-softmax partials (software-pipelined nontemporal stream),
// then the last-arriving block of each batch combines that batch's partials.
__global__ __launch_bounds__(256) void pool_fused(
    const float* __restrict__ x, const float* __restrict__ w,
    float* __restrict__ acc_ws, float* __restrict__ ml_ws,
    unsigned int* __restrict__ cnt, float* __restrict__ out,
    int T, int C, int RPW)
{
    const int b    = blockIdx.y;
    const int wave = threadIdx.x >> 6;
    const int lane = threadIdx.x & 63;
    const int chunk = blockIdx.x * 4 + wave;
    const int tid  = threadIdx.x;

    __shared__ unsigned int s_old;
    __shared__ float s_e[256];   // C <= 256
    __shared__ float red[256];

    // ---------------- streaming pass ----------------
    {
        const fx4 wa = *(const fx4*)(w + 4 * lane);
        const fx4 wb = *(const fx4*)(w + 256 + 4 * lane);

        float m = -INFINITY, l = 0.0f;
        fx4 a0 = (fx4)0.0f;
        fx4 a1 = (fx4)0.0f;

        const float* xr = x + (size_t)b * T * D_MODEL + (size_t)chunk * RPW * D_MODEL;

        // prologue: load rows 0..3
        fx4 c0a = NTL(xr                   + 4 * lane);
        fx4 c0b = NTL(xr             + 256 + 4 * lane);
        fx4 c1a = NTL(xr + 1*D_MODEL       + 4 * lane);
        fx4 c1b = NTL(xr + 1*D_MODEL + 256 + 4 * lane);
        fx4 c2a = NTL(xr + 2*D_MODEL       + 4 * lane);
        fx4 c2b = NTL(xr + 2*D_MODEL + 256 + 4 * lane);
        fx4 c3a = NTL(xr + 3*D_MODEL       + 4 * lane);
        fx4 c3b = NTL(xr + 3*D_MODEL + 256 + 4 * lane);

        for (int r = 0; r < RPW - 4; r += 4) {
            xr += 4 * D_MODEL;
            // issue next block's loads before consuming current block
            const fx4 n0a = NTL(xr                   + 4 * lane);
            const fx4 n0b = NTL(xr             + 256 + 4 * lane);
            const fx4 n1a = NTL(xr + 1*D_MODEL       + 4 * lane);
            const fx4 n1b = NTL(xr + 1*D_MODEL + 256 + 4 * lane);
            const fx4 n2a = NTL(xr + 2*D_MODEL       + 4 * lane);
            const fx4 n2b = NTL(xr + 2*D_MODEL + 256 + 4 * lane);
            const fx4 n3a = NTL(xr + 3*D_MODEL       + 4 * lane);
            const fx4 n3b = NTL(xr + 3*D_MODEL + 256 + 4 * lane);

            process4(c0a, c0b, c1a, c1b, c2a, c2b, c3a, c3b, wa, wb, m, l, a0, a1);

            c0a = n0a; c0b = n0b; c1a = n1a; c1b = n1b;
            c2a = n2a; c2b = n2b; c3a = n3a; c3b = n3b;
        }
        process4(c0a, c0b, c1a, c1b, c2a, c2b, c3a, c3b, wa, wb, m, l, a0, a1);

        float* accp = acc_ws + (size_t)(b * C + chunk) * D_MODEL;
        *(fx4*)(accp + 4 * lane)       = a0;
        *(fx4*)(accp + 256 + 4 * lane) = a1;
        if (lane == 0) {
            ml_ws[(b * C + chunk) * 2 + 0] = m;
            ml_ws[(b * C + chunk) * 2 + 1] = l;
        }
    }

    // ---------------- last-block-per-batch combine ----------------
    __threadfence();              // release partials device-wide (cross-XCD)
    __syncthreads();
    if (tid == 0) s_old = atomicAdd(&cnt[b], 1u);
    __syncthreads();
    if (s_old != (unsigned)(C / 4 - 1)) return;   // block-uniform
    __threadfence();              // acquire: invalidate stale lines

    // block max of m over C chunks
    float mloc = -INFINITY;
    for (int c = tid; c < C; c += 256)
        mloc = fmaxf(mloc, ml_ws[(b * C + c) * 2 + 0]);
    red[tid] = mloc;
    __syncthreads();
    for (int s = 128; s > 0; s >>= 1) {
        if (tid < s) red[tid] = fmaxf(red[tid], red[tid + s]);
        __syncthreads();
    }
    const float M = red[0];
    __syncthreads();

    // per-chunk scale e_c = exp(m_c - M); L = sum e_c * l_c
    float lloc = 0.0f;
    for (int c = tid; c < C; c += 256) {
        const float e = __expf(ml_ws[(b * C + c) * 2 + 0] - M);
        s_e[c] = e;
        lloc += e * ml_ws[(b * C + c) * 2 + 1];
    }
    red[tid] = lloc;
    __syncthreads();
    for (int s = 128; s > 0; s >>= 1) {
        if (tid < s) red[tid] += red[tid + s];
        __syncthreads();
    }
    const float L = red[0];

    // weighted sum over chunks; thread owns columns tid and tid+256
    float s0 = 0.0f, s1 = 0.0f;
    const float* basep = acc_ws + (size_t)b * C * D_MODEL;
    for (int c = 0; c < C; ++c) {
        const float e = s_e[c];
        s0 = fmaf(e, basep[(size_t)c * D_MODEL + tid], s0);
        s1 = fmaf(e, basep[(size_t)c * D_MODEL + tid + 256], s1);
    }
    const float inv = 1.0f / L;
    out[b * D_MODEL + tid]       = s0 * inv;
    out[b * D_MODEL + tid + 256] = s1 * inv;
}

extern "C" void kernel_launch(void* const* d_in, const int* in_sizes, int n_in,
                              void* d_out, int out_size, void* d_ws, size_t ws_size,
                              hipStream_t stream)
{
    const float* x = (const float*)d_in[0];
    const float* w = (const float*)d_in[1];
    // d_in[2] (bias) intentionally ignored: softmax is shift-invariant.
    float* out = (float*)d_out;

    const int D = D_MODEL;
    const int B = 32;
    const int T = in_sizes[0] / (B * D);   // 8192

    int C = 128;
    while (C > 8) {
        size_t need = (size_t)B * C * D * sizeof(float)
                    + (size_t)B * C * 2 * sizeof(float)
                    + (size_t)B * sizeof(unsigned int);
        if (need <= ws_size) break;
        C >>= 1;
    }
    const int RPW = T / C;                 // 64 (multiple of 4, >= 8)

    float* acc_ws = (float*)d_ws;
    float* ml_ws  = acc_ws + (size_t)B * C * D;
    unsigned int* cnt = (unsigned int*)(ml_ws + (size_t)B * C * 2);

    hipMemsetAsync(cnt, 0, B * sizeof(unsigned int), stream);

    dim3 grid(C / 4, B);
    pool_fused<<<grid, 256, 0, stream>>>(x, w, acc_ws, ml_ws, cnt, out, T, C, RPW);
}

// Round 7
// 112.013 us; speedup vs baseline: 2.8580x; 2.8580x over previous
//
#include <hip/hip_runtime.h>
#include <math.h>

#define D_MODEL 512  // kernels assume D=512 (64 lanes x 8 floats)

typedef float fx4 __attribute__((ext_vector_type(4)));

#define NTL(p) __builtin_nontemporal_load((const fx4*)(p))

__device__ __forceinline__ float dot8(const fx4& a0, const fx4& a1,
                                      const fx4& b0, const fx4& b1) {
    return a0.x * b0.x + a0.y * b0.y + a0.z * b0.z + a0.w * b0.w
         + a1.x * b1.x + a1.y * b1.y + a1.z * b1.z + a1.w * b1.w;
}

// Online-softmax update for a block of 4 rows held in registers.
__device__ __forceinline__ void process4(
    const fx4& r0a, const fx4& r0b, const fx4& r1a, const fx4& r1b,
    const fx4& r2a, const fx4& r2b, const fx4& r3a, const fx4& r3b,
    const fx4& wa, const fx4& wb,
    float& m, float& l, fx4& a0, fx4& a1)
{
    float d0 = dot8(r0a, r0b, wa, wb);
    float d1 = dot8(r1a, r1b, wa, wb);
    float d2 = dot8(r2a, r2b, wa, wb);
    float d3 = dot8(r3a, r3b, wa, wb);
    #pragma unroll
    for (int off = 32; off >= 1; off >>= 1) {   // 4 interleaved chains
        d0 += __shfl_xor(d0, off);
        d1 += __shfl_xor(d1, off);
        d2 += __shfl_xor(d2, off);
        d3 += __shfl_xor(d3, off);
    }
    const float mx = fmaxf(fmaxf(d0, d1), fmaxf(d2, d3));
    if (mx > m) {                        // wave-uniform, rare (~log RPW)
        const float sc = __expf(m - mx); // first hit: exp(-inf)=0, acc is 0
        l *= sc;
        a0 *= sc;
        a1 *= sc;
        m = mx;
    }
    const float p0 = __expf(d0 - m);
    const float p1 = __expf(d1 - m);
    const float p2 = __expf(d2 - m);
    const float p3 = __expf(d3 - m);
    l += (p0 + p1) + (p2 + p3);
    a0 += p0 * r0a; a1 += p0 * r0b;
    a0 += p1 * r1a; a1 += p1 * r1b;
    a0 += p2 * r2a; a1 += p2 * r2b;
    a0 += p3 * r3a; a1 += p3 * r3b;
}

// Pass 1: online-softmax partials, 4 rows/iter, software-pipelined one stage:
// iteration k+1's 8 nontemporal loads are issued BEFORE iteration k's
// shfl/exp/fma chain, so HBM latency hides under compute.
__global__ __launch_bounds__(256) void pool_pass1(
    const float* __restrict__ x, const float* __restrict__ w,
    float* __restrict__ acc_ws, float* __restrict__ ml_ws,
    int T, int C, int RPW)
{
    const int b    = blockIdx.y;
    const int wave = threadIdx.x >> 6;
    const int lane = threadIdx.x & 63;
    const int chunk = blockIdx.x * 4 + wave;

    const fx4 wa = *(const fx4*)(w + 4 * lane);
    const fx4 wb = *(const fx4*)(w + 256 + 4 * lane);

    float m = -INFINITY, l = 0.0f;
    fx4 a0 = (fx4)0.0f;
    fx4 a1 = (fx4)0.0f;

    const float* xr = x + (size_t)b * T * D_MODEL + (size_t)chunk * RPW * D_MODEL;

    // prologue: load rows 0..3
    fx4 c0a = NTL(xr                   + 4 * lane);
    fx4 c0b = NTL(xr             + 256 + 4 * lane);
    fx4 c1a = NTL(xr + 1*D_MODEL       + 4 * lane);
    fx4 c1b = NTL(xr + 1*D_MODEL + 256 + 4 * lane);
    fx4 c2a = NTL(xr + 2*D_MODEL       + 4 * lane);
    fx4 c2b = NTL(xr + 2*D_MODEL + 256 + 4 * lane);
    fx4 c3a = NTL(xr + 3*D_MODEL       + 4 * lane);
    fx4 c3b = NTL(xr + 3*D_MODEL + 256 + 4 * lane);

    for (int r = 0; r < RPW - 4; r += 4) {
        xr += 4 * D_MODEL;
        // issue next block's loads first (independent registers)
        const fx4 n0a = NTL(xr                   + 4 * lane);
        const fx4 n0b = NTL(xr             + 256 + 4 * lane);
        const fx4 n1a = NTL(xr + 1*D_MODEL       + 4 * lane);
        const fx4 n1b = NTL(xr + 1*D_MODEL + 256 + 4 * lane);
        const fx4 n2a = NTL(xr + 2*D_MODEL       + 4 * lane);
        const fx4 n2b = NTL(xr + 2*D_MODEL + 256 + 4 * lane);
        const fx4 n3a = NTL(xr + 3*D_MODEL       + 4 * lane);
        const fx4 n3b = NTL(xr + 3*D_MODEL + 256 + 4 * lane);

        process4(c0a, c0b, c1a, c1b, c2a, c2b, c3a, c3b, wa, wb, m, l, a0, a1);

        c0a = n0a; c0b = n0b; c1a = n1a; c1b = n1b;   // register rotate
        c2a = n2a; c2b = n2b; c3a = n3a; c3b = n3b;   // (renamed by compiler)
    }
    process4(c0a, c0b, c1a, c1b, c2a, c2b, c3a, c3b, wa, wb, m, l, a0, a1);

    float* accp = acc_ws + (size_t)(b * C + chunk) * D_MODEL;
    *(fx4*)(accp + 4 * lane)       = a0;
    *(fx4*)(accp + 256 + 4 * lane) = a1;
    if (lane == 0) {
        ml_ws[(b * C + chunk) * 2 + 0] = m;
        ml_ws[(b * C + chunk) * 2 + 1] = l;
    }
}

// Pass 2: combine chunk partials. grid=(B,4), block=256.
__global__ __launch_bounds__(256) void pool_pass2(
    const float* __restrict__ acc_ws, const float* __restrict__ ml_ws,
    float* __restrict__ out, int C)
{
    const int b   = blockIdx.x;
    const int q   = blockIdx.y;
    const int tid = threadIdx.x;
    const int fx  = tid & 31;
    const int cg  = tid >> 5;

    __shared__ float s_e[256];
    __shared__ float red[256];
    __shared__ fx4   s_acc[256];

    float mloc = -INFINITY;
    for (int c = tid; c < C; c += 256)
        mloc = fmaxf(mloc, ml_ws[(b * C + c) * 2 + 0]);
    red[tid] = mloc;
    __syncthreads();
    for (int s = 128; s > 0; s >>= 1) {
        if (tid < s) red[tid] = fmaxf(red[tid], red[tid + s]);
        __syncthreads();
    }
    const float M = red[0];
    __syncthreads();

    float lloc = 0.0f;
    for (int c = tid; c < C; c += 256) {
        const float e = __expf(ml_ws[(b * C + c) * 2 + 0] - M);
        s_e[c] = e;
        lloc += e * ml_ws[(b * C + c) * 2 + 1];
    }
    red[tid] = lloc;
    __syncthreads();
    for (int s = 128; s > 0; s >>= 1) {
        if (tid < s) red[tid] += red[tid + s];
        __syncthreads();
    }
    const float L = red[0];
    __syncthreads();

    fx4 sum = (fx4)0.0f;
    const float* base = acc_ws + (size_t)b * C * D_MODEL + q * 128 + fx * 4;
    for (int c = cg; c < C; c += 8) {
        sum += s_e[c] * *(const fx4*)(base + (size_t)c * D_MODEL);
    }
    s_acc[tid] = sum;
    __syncthreads();
    if (cg == 0) {
        fx4 t = s_acc[fx];
        #pragma unroll
        for (int g = 1; g < 8; ++g) t += s_acc[g * 32 + fx];
        const float inv = 1.0f / L;
        t *= inv;
        float* op = out + b * D_MODEL + q * 128 + fx * 4;
        *(fx4*)op = t;
    }
}

extern "C" void kernel_launch(void* const* d_in, const int* in_sizes, int n_in,
                              void* d_out, int out_size, void* d_ws, size_t ws_size,
                              hipStream_t stream)
{
    const float* x = (const float*)d_in[0];
    const float* w = (const float*)d_in[1];
    // d_in[2] (bias) intentionally ignored: softmax is shift-invariant.
    float* out = (float*)d_out;

    const int D = D_MODEL;
    const int B = 32;
    const int T = in_sizes[0] / (B * D);   // 8192

    // C=256 -> 8192 waves = 32/CU = 8/SIMD (VGPR=56 permits it); RPW=32.
    int C = 256;
    while (C > 8) {
        size_t need = (size_t)B * C * D * sizeof(float) + (size_t)B * C * 2 * sizeof(float);
        if (need <= ws_size) break;
        C >>= 1;
    }
    const int RPW = T / C;                 // 32 (multiple of 4, >= 8)

    float* acc_ws = (float*)d_ws;
    float* ml_ws  = acc_ws + (size_t)B * C * D;

    dim3 grid1(C / 4, B);
    pool_pass1<<<grid1, 256, 0, stream>>>(x, w, acc_ws, ml_ws, T, C, RPW);
    pool_pass2<<<dim3(B, 4), 256, 0, stream>>>(acc_ws, ml_ws, out, C);
}

// Round 9
// 99.388 us; speedup vs baseline: 3.2211x; 1.1270x over previous
//
#include <hip/hip_runtime.h>
#include <math.h>

#define D_MODEL 512  // kernels assume D=512 (64 lanes x 8 floats)

typedef float fx4 __attribute__((ext_vector_type(4)));

#define NTL(p)    __builtin_nontemporal_load((const fx4*)(p))
#define NTLF(p)   __builtin_nontemporal_load((const float*)(p))
#define NTS(p, v) __builtin_nontemporal_store((v), (fx4*)(p))
#define NTSF(p, v) __builtin_nontemporal_store((v), (float*)(p))

__device__ __forceinline__ float dot8(const fx4& a0, const fx4& a1,
                                      const fx4& b0, const fx4& b1) {
    return a0.x * b0.x + a0.y * b0.y + a0.z * b0.z + a0.w * b0.w
         + a1.x * b1.x + a1.y * b1.y + a1.z * b1.z + a1.w * b1.w;
}

// Online-softmax update for a block of 4 rows held in registers.
__device__ __forceinline__ void process4(
    const fx4& r0a, const fx4& r0b, const fx4& r1a, const fx4& r1b,
    const fx4& r2a, const fx4& r2b, const fx4& r3a, const fx4& r3b,
    const fx4& wa, const fx4& wb,
    float& m, float& l, fx4& a0, fx4& a1)
{
    float d0 = dot8(r0a, r0b, wa, wb);
    float d1 = dot8(r1a, r1b, wa, wb);
    float d2 = dot8(r2a, r2b, wa, wb);
    float d3 = dot8(r3a, r3b, wa, wb);
    #pragma unroll
    for (int off = 32; off >= 1; off >>= 1) {   // 4 interleaved chains
        d0 += __shfl_xor(d0, off);
        d1 += __shfl_xor(d1, off);
        d2 += __shfl_xor(d2, off);
        d3 += __shfl_xor(d3, off);
    }
    const float mx = fmaxf(fmaxf(d0, d1), fmaxf(d2, d3));
    if (mx > m) {                        // wave-uniform, rare (~log RPW)
        const float sc = __expf(m - mx); // first hit: exp(-inf)=0, acc is 0
        l *= sc;
        a0 *= sc;
        a1 *= sc;
        m = mx;
    }
    const float p0 = __expf(d0 - m);
    const float p1 = __expf(d1 - m);
    const float p2 = __expf(d2 - m);
    const float p3 = __expf(d3 - m);
    l += (p0 + p1) + (p2 + p3);
    a0 += p0 * r0a; a1 += p0 * r0b;
    a0 += p1 * r1a; a1 += p1 * r1b;
    a0 += p2 * r2a; a1 += p2 * r2b;
    a0 += p3 * r3a; a1 += p3 * r3b;
}

// Pass 1: online-softmax partials, 4 rows/iter, software-pipelined one stage.
// Partials are written with NON-TEMPORAL stores: no reuse in this kernel, and
// the nt flag avoids leaving dirty lines in the producer XCD's L2 (replay-
// staleness hazard seen in R8; partials are consumed by pass2 on other XCDs).
__global__ __launch_bounds__(256) void pool_pass1(
    const float* __restrict__ x, const float* __restrict__ w,
    float* __restrict__ acc_ws, float* __restrict__ ml_ws,
    int T, int C, int RPW)
{
    const int b    = blockIdx.y;
    const int wave = threadIdx.x >> 6;
    const int lane = threadIdx.x & 63;
    const int chunk = blockIdx.x * 4 + wave;

    const fx4 wa = *(const fx4*)(w + 4 * lane);
    const fx4 wb = *(const fx4*)(w + 256 + 4 * lane);

    float m = -INFINITY, l = 0.0f;
    fx4 a0 = (fx4)0.0f;
    fx4 a1 = (fx4)0.0f;

    const float* xr = x + (size_t)b * T * D_MODEL + (size_t)chunk * RPW * D_MODEL;

    // prologue: load rows 0..3
    fx4 c0a = NTL(xr                   + 4 * lane);
    fx4 c0b = NTL(xr             + 256 + 4 * lane);
    fx4 c1a = NTL(xr + 1*D_MODEL       + 4 * lane);
    fx4 c1b = NTL(xr + 1*D_MODEL + 256 + 4 * lane);
    fx4 c2a = NTL(xr + 2*D_MODEL       + 4 * lane);
    fx4 c2b = NTL(xr + 2*D_MODEL + 256 + 4 * lane);
    fx4 c3a = NTL(xr + 3*D_MODEL       + 4 * lane);
    fx4 c3b = NTL(xr + 3*D_MODEL + 256 + 4 * lane);

    for (int r = 0; r < RPW - 4; r += 4) {
        xr += 4 * D_MODEL;
        // issue next block's loads first (independent registers)
        const fx4 n0a = NTL(xr                   + 4 * lane);
        const fx4 n0b = NTL(xr             + 256 + 4 * lane);
        const fx4 n1a = NTL(xr + 1*D_MODEL       + 4 * lane);
        const fx4 n1b = NTL(xr + 1*D_MODEL + 256 + 4 * lane);
        const fx4 n2a = NTL(xr + 2*D_MODEL       + 4 * lane);
        const fx4 n2b = NTL(xr + 2*D_MODEL + 256 + 4 * lane);
        const fx4 n3a = NTL(xr + 3*D_MODEL       + 4 * lane);
        const fx4 n3b = NTL(xr + 3*D_MODEL + 256 + 4 * lane);

        process4(c0a, c0b, c1a, c1b, c2a, c2b, c3a, c3b, wa, wb, m, l, a0, a1);

        c0a = n0a; c0b = n0b; c1a = n1a; c1b = n1b;   // register rotate
        c2a = n2a; c2b = n2b; c3a = n3a; c3b = n3b;   // (renamed by compiler)
    }
    process4(c0a, c0b, c1a, c1b, c2a, c2b, c3a, c3b, wa, wb, m, l, a0, a1);

    float* accp = acc_ws + (size_t)(b * C + chunk) * D_MODEL;
    NTS(accp + 4 * lane, a0);
    NTS(accp + 256 + 4 * lane, a1);
    if (lane == 0) {
        NTSF(&ml_ws[(b * C + chunk) * 2 + 0], m);
        NTSF(&ml_ws[(b * C + chunk) * 2 + 1], l);
    }
}

// Pass 2: combine chunk partials. grid=(B,4), block=256.
// All workspace reads are non-temporal (single-use data; bypass stale copies).
__global__ __launch_bounds__(256) void pool_pass2(
    const float* __restrict__ acc_ws, const float* __restrict__ ml_ws,
    float* __restrict__ out, int C)
{
    const int b   = blockIdx.x;
    const int q   = blockIdx.y;
    const int tid = threadIdx.x;
    const int fx  = tid & 31;
    const int cg  = tid >> 5;

    __shared__ float s_e[256];
    __shared__ float red[256];
    __shared__ fx4   s_acc[256];

    float mloc = -INFINITY;
    for (int c = tid; c < C; c += 256)
        mloc = fmaxf(mloc, NTLF(&ml_ws[(b * C + c) * 2 + 0]));
    red[tid] = mloc;
    __syncthreads();
    for (int s = 128; s > 0; s >>= 1) {
        if (tid < s) red[tid] = fmaxf(red[tid], red[tid + s]);
        __syncthreads();
    }
    const float M = red[0];
    __syncthreads();

    float lloc = 0.0f;
    for (int c = tid; c < C; c += 256) {
        const float e = __expf(NTLF(&ml_ws[(b * C + c) * 2 + 0]) - M);
        s_e[c] = e;
        lloc += e * NTLF(&ml_ws[(b * C + c) * 2 + 1]);
    }
    red[tid] = lloc;
    __syncthreads();
    for (int s = 128; s > 0; s >>= 1) {
        if (tid < s) red[tid] += red[tid + s];
        __syncthreads();
    }
    const float L = red[0];
    __syncthreads();

    fx4 sum = (fx4)0.0f;
    const float* base = acc_ws + (size_t)b * C * D_MODEL + q * 128 + fx * 4;
    for (int c = cg; c < C; c += 8) {
        sum += s_e[c] * NTL(base + (size_t)c * D_MODEL);
    }
    s_acc[tid] = sum;
    __syncthreads();
    if (cg == 0) {
        fx4 t = s_acc[fx];
        #pragma unroll
        for (int g = 1; g < 8; ++g) t += s_acc[g * 32 + fx];
        const float inv = 1.0f / L;
        t *= inv;
        float* op = out + b * D_MODEL + q * 128 + fx * 4;
        *(fx4*)op = t;
    }
}

extern "C" void kernel_launch(void* const* d_in, const int* in_sizes, int n_in,
                              void* d_out, int out_size, void* d_ws, size_t ws_size,
                              hipStream_t stream)
{
    const float* x = (const float*)d_in[0];
    const float* w = (const float*)d_in[1];
    // d_in[2] (bias) intentionally ignored: softmax is shift-invariant.
    float* out = (float*)d_out;

    const int D = D_MODEL;
    const int B = 32;
    const int T = in_sizes[0] / (B * D);   // 8192

    // C=64 -> 2048 waves = 8/CU, streams of 262KB/wave (page locality), RPW=128.
    int C = 64;
    while (C > 8) {
        size_t need = (size_t)B * C * D * sizeof(float) + (size_t)B * C * 2 * sizeof(float);
        if (need <= ws_size) break;
        C >>= 1;
    }
    const int RPW = T / C;                 // 128 (multiple of 4, >= 8)

    float* acc_ws = (float*)d_ws;
    float* ml_ws  = acc_ws + (size_t)B * C * D;

    dim3 grid1(C / 4, B);
    pool_pass1<<<grid1, 256, 0, stream>>>(x, w, acc_ws, ml_ws, T, C, RPW);
    pool_pass2<<<dim3(B, 4), 256, 0, stream>>>(acc_ws, ml_ws, out, C);
}

// Round 10
// 89.056 us; speedup vs baseline: 3.5948x; 1.1160x over previous
//
#include <hip/hip_runtime.h>
#include <math.h>

#define D_MODEL 512  // kernels assume D=512 (64 lanes x 8 floats)

typedef float fx4 __attribute__((ext_vector_type(4)));

#define NTL(p)    __builtin_nontemporal_load((const fx4*)(p))
#define NTLF(p)   __builtin_nontemporal_load((const float*)(p))
#define NTS(p, v) __builtin_nontemporal_store((v), (fx4*)(p))
#define NTSF(p, v) __builtin_nontemporal_store((v), (float*)(p))

__device__ __forceinline__ float dot8(const fx4& a0, const fx4& a1,
                                      const fx4& b0, const fx4& b1) {
    return a0.x * b0.x + a0.y * b0.y + a0.z * b0.z + a0.w * b0.w
         + a1.x * b1.x + a1.y * b1.y + a1.z * b1.z + a1.w * b1.w;
}

// Online-softmax update for a block of 4 rows held in registers.
__device__ __forceinline__ void process4(
    const fx4& r0a, const fx4& r0b, const fx4& r1a, const fx4& r1b,
    const fx4& r2a, const fx4& r2b, const fx4& r3a, const fx4& r3b,
    const fx4& wa, const fx4& wb,
    float& m, float& l, fx4& a0, fx4& a1)
{
    float d0 = dot8(r0a, r0b, wa, wb);
    float d1 = dot8(r1a, r1b, wa, wb);
    float d2 = dot8(r2a, r2b, wa, wb);
    float d3 = dot8(r3a, r3b, wa, wb);
    #pragma unroll
    for (int off = 32; off >= 1; off >>= 1) {   // 4 interleaved chains
        d0 += __shfl_xor(d0, off);
        d1 += __shfl_xor(d1, off);
        d2 += __shfl_xor(d2, off);
        d3 += __shfl_xor(d3, off);
    }
    const float mx = fmaxf(fmaxf(d0, d1), fmaxf(d2, d3));
    if (mx > m) {                        // wave-uniform, rare (~log RPW)
        const float sc = __expf(m - mx); // first hit: exp(-inf)=0, acc is 0
        l *= sc;
        a0 *= sc;
        a1 *= sc;
        m = mx;
    }
    const float p0 = __expf(d0 - m);
    const float p1 = __expf(d1 - m);
    const float p2 = __expf(d2 - m);
    const float p3 = __expf(d3 - m);
    l += (p0 + p1) + (p2 + p3);
    a0 += p0 * r0a; a1 += p0 * r0b;
    a0 += p1 * r1a; a1 += p1 * r1b;
    a0 += p2 * r2a; a1 += p2 * r2b;
    a0 += p3 * r3a; a1 += p3 * r3b;
}

// Pass 1: online-softmax partials, 4 rows/iter, software-pipelined one stage.
// Partials written with NON-TEMPORAL stores (single-use; avoids dirty-L2
// replay-staleness across XCDs seen in R8).
__global__ __launch_bounds__(256) void pool_pass1(
    const float* __restrict__ x, const float* __restrict__ w,
    float* __restrict__ acc_ws, float* __restrict__ ml_ws,
    int T, int C, int RPW)
{
    const int b    = blockIdx.y;
    const int wave = threadIdx.x >> 6;
    const int lane = threadIdx.x & 63;
    const int chunk = blockIdx.x * 4 + wave;

    const fx4 wa = *(const fx4*)(w + 4 * lane);
    const fx4 wb = *(const fx4*)(w + 256 + 4 * lane);

    float m = -INFINITY, l = 0.0f;
    fx4 a0 = (fx4)0.0f;
    fx4 a1 = (fx4)0.0f;

    const float* xr = x + (size_t)b * T * D_MODEL + (size_t)chunk * RPW * D_MODEL;

    // prologue: load rows 0..3
    fx4 c0a = NTL(xr                   + 4 * lane);
    fx4 c0b = NTL(xr             + 256 + 4 * lane);
    fx4 c1a = NTL(xr + 1*D_MODEL       + 4 * lane);
    fx4 c1b = NTL(xr + 1*D_MODEL + 256 + 4 * lane);
    fx4 c2a = NTL(xr + 2*D_MODEL       + 4 * lane);
    fx4 c2b = NTL(xr + 2*D_MODEL + 256 + 4 * lane);
    fx4 c3a = NTL(xr + 3*D_MODEL       + 4 * lane);
    fx4 c3b = NTL(xr + 3*D_MODEL + 256 + 4 * lane);

    for (int r = 0; r < RPW - 4; r += 4) {
        xr += 4 * D_MODEL;
        // issue next block's loads first (independent registers)
        const fx4 n0a = NTL(xr                   + 4 * lane);
        const fx4 n0b = NTL(xr             + 256 + 4 * lane);
        const fx4 n1a = NTL(xr + 1*D_MODEL       + 4 * lane);
        const fx4 n1b = NTL(xr + 1*D_MODEL + 256 + 4 * lane);
        const fx4 n2a = NTL(xr + 2*D_MODEL       + 4 * lane);
        const fx4 n2b = NTL(xr + 2*D_MODEL + 256 + 4 * lane);
        const fx4 n3a = NTL(xr + 3*D_MODEL       + 4 * lane);
        const fx4 n3b = NTL(xr + 3*D_MODEL + 256 + 4 * lane);

        process4(c0a, c0b, c1a, c1b, c2a, c2b, c3a, c3b, wa, wb, m, l, a0, a1);

        c0a = n0a; c0b = n0b; c1a = n1a; c1b = n1b;   // register rotate
        c2a = n2a; c2b = n2b; c3a = n3a; c3b = n3b;   // (renamed by compiler)
    }
    process4(c0a, c0b, c1a, c1b, c2a, c2b, c3a, c3b, wa, wb, m, l, a0, a1);

    float* accp = acc_ws + (size_t)(b * C + chunk) * D_MODEL;
    NTS(accp + 4 * lane, a0);
    NTS(accp + 256 + 4 * lane, a1);
    if (lane == 0) {
        NTSF(&ml_ws[(b * C + chunk) * 2 + 0], m);
        NTSF(&ml_ws[(b * C + chunk) * 2 + 1], l);
    }
}

// Pass 2: combine chunk partials. grid=(B,4), block=256.
// All workspace reads are non-temporal (single-use data; bypass stale copies).
__global__ __launch_bounds__(256) void pool_pass2(
    const float* __restrict__ acc_ws, const float* __restrict__ ml_ws,
    float* __restrict__ out, int C)
{
    const int b   = blockIdx.x;
    const int q   = blockIdx.y;
    const int tid = threadIdx.x;
    const int fx  = tid & 31;
    const int cg  = tid >> 5;

    __shared__ float s_e[256];
    __shared__ float red[256];
    __shared__ fx4   s_acc[256];

    float mloc = -INFINITY;
    for (int c = tid; c < C; c += 256)
        mloc = fmaxf(mloc, NTLF(&ml_ws[(b * C + c) * 2 + 0]));
    red[tid] = mloc;
    __syncthreads();
    for (int s = 128; s > 0; s >>= 1) {
        if (tid < s) red[tid] = fmaxf(red[tid], red[tid + s]);
        __syncthreads();
    }
    const float M = red[0];
    __syncthreads();

    float lloc = 0.0f;
    for (int c = tid; c < C; c += 256) {
        const float e = __expf(NTLF(&ml_ws[(b * C + c) * 2 + 0]) - M);
        s_e[c] = e;
        lloc += e * NTLF(&ml_ws[(b * C + c) * 2 + 1]);
    }
    red[tid] = lloc;
    __syncthreads();
    for (int s = 128; s > 0; s >>= 1) {
        if (tid < s) red[tid] += red[tid + s];
        __syncthreads();
    }
    const float L = red[0];
    __syncthreads();

    fx4 sum = (fx4)0.0f;
    const float* base = acc_ws + (size_t)b * C * D_MODEL + q * 128 + fx * 4;
    for (int c = cg; c < C; c += 8) {
        sum += s_e[c] * NTL(base + (size_t)c * D_MODEL);
    }
    s_acc[tid] = sum;
    __syncthreads();
    if (cg == 0) {
        fx4 t = s_acc[fx];
        #pragma unroll
        for (int g = 1; g < 8; ++g) t += s_acc[g * 32 + fx];
        const float inv = 1.0f / L;
        t *= inv;
        float* op = out + b * D_MODEL + q * 128 + fx * 4;
        *(fx4*)op = t;
    }
}

extern "C" void kernel_launch(void* const* d_in, const int* in_sizes, int n_in,
                              void* d_out, int out_size, void* d_ws, size_t ws_size,
                              hipStream_t stream)
{
    const float* x = (const float*)d_in[0];
    const float* w = (const float*)d_in[1];
    // d_in[2] (bias) intentionally ignored: softmax is shift-invariant.
    float* out = (float*)d_out;

    const int D = D_MODEL;
    const int B = 32;
    const int T = in_sizes[0] / (B * D);   // 8192

    // C=32 -> 1024 waves, 256 blocks = exactly 1 block/CU; 1 MB stream/wave.
    int C = 32;
    while (C > 8) {
        size_t need = (size_t)B * C * D * sizeof(float) + (size_t)B * C * 2 * sizeof(float);
        if (need <= ws_size) break;
        C >>= 1;
    }
    const int RPW = T / C;                 // 256 (multiple of 4, >= 8)

    float* acc_ws = (float*)d_ws;
    float* ml_ws  = acc_ws + (size_t)B * C * D;

    dim3 grid1(C / 4, B);
    pool_pass1<<<grid1, 256, 0, stream>>>(x, w, acc_ws, ml_ws, T, C, RPW);
    pool_pass2<<<dim3(B, 4), 256, 0, stream>>>(acc_ws, ml_ws, out, C);
}